// Round 1
// baseline (231.112 us; speedup 1.0000x reference)
//
#include <hip/hip_runtime.h>
#include <stdint.h>

#define B_ 4
#define T_ 2048
#define C_ 1024
#define H_ 128
#define NEG_BIG -3.0e38f

typedef __attribute__((ext_vector_type(8))) short short8;
typedef __attribute__((ext_vector_type(4))) float f32x4;
typedef __attribute__((ext_vector_type(4))) unsigned short ushort4v;

__device__ __forceinline__ unsigned short f2bf(float f) {
  union { float f; unsigned u; } cv; cv.f = f;
  unsigned u = cv.u;
  return (unsigned short)((u + 0x7fffu + ((u >> 16) & 1u)) >> 16);  // RNE
}

__device__ __forceinline__ float bf2f(unsigned short s) {
  union { unsigned u; float f; } cv; cv.u = ((unsigned)s) << 16;
  return cv.f;
}

// ---------------------------------------------------------------------------
// Kernel 1: cast Wq|Wk|Wv (fp32 [1024][128] each) into WbT bf16 [384][1024]
// (transposed so MFMA B-fragments = 16B contiguous loads: 8 consecutive k)
// ---------------------------------------------------------------------------
__global__ __launch_bounds__(256) void prep_w(const float* __restrict__ Wq,
                                              const float* __restrict__ Wk,
                                              const float* __restrict__ Wv,
                                              unsigned short* __restrict__ WbT) {
  int idx = blockIdx.x * 256 + threadIdx.x;   // 0 .. 384*1024-1
  int j = idx >> 10;                          // output row 0..383
  int k = idx & 1023;
  const float* W = (j < 128) ? Wq : (j < 256) ? Wk : Wv;
  int h = j & 127;
  WbT[idx] = f2bf(W[k * 128 + h]);
}

// ---------------------------------------------------------------------------
// Kernel 2: QKV projection. x[8192][1024] fp32 @ W[1024][384] -> bf16 outputs.
// Direct-fragment GEMM (no LDS): A-frags = fp32 loads + in-reg cvt,
// B-frags = contiguous 16B loads from WbT (L1/L2 resident).
// Block = 32 rows, 4 waves: wave = (rowhalf = w&1 -> 16 rows, nhalf = w>>1 -> 192 cols)
// Writes Qb[8192][128], Kb[8192][128], VT[4][128][2048] (V transposed).
// ---------------------------------------------------------------------------
__global__ __launch_bounds__(256) void qkv_proj(const float* __restrict__ x,
                                                const unsigned short* __restrict__ WbT,
                                                unsigned short* __restrict__ Qb,
                                                unsigned short* __restrict__ Kb,
                                                unsigned short* __restrict__ VT) {
  const int tid  = threadIdx.x;
  const int wave = tid >> 6, lane = tid & 63;
  const int quad = lane >> 4, l15 = lane & 15;
  const int m0    = blockIdx.x * 32 + ((wave & 1) << 4);  // this wave's 16-row base
  const int nbase = (wave >> 1) * 192;

  f32x4 acc[12];
  const f32x4 zero4 = {0.f, 0.f, 0.f, 0.f};
#pragma unroll
  for (int i = 0; i < 12; ++i) acc[i] = zero4;

  const float* xrow = x + (size_t)(m0 + l15) * C_;

  for (int ks = 0; ks < 32; ++ks) {
    const int k0 = ks * 32 + quad * 8;
    // A fragment: A[m=l15][k=quad*8+j], fp32 -> bf16 in registers
    f32x4 a0 = *(const f32x4*)(xrow + k0);
    f32x4 a1 = *(const f32x4*)(xrow + k0 + 4);
    short8 af;
    af[0] = (short)f2bf(a0[0]); af[1] = (short)f2bf(a0[1]);
    af[2] = (short)f2bf(a0[2]); af[3] = (short)f2bf(a0[3]);
    af[4] = (short)f2bf(a1[0]); af[5] = (short)f2bf(a1[1]);
    af[6] = (short)f2bf(a1[2]); af[7] = (short)f2bf(a1[3]);
#pragma unroll
    for (int nt = 0; nt < 12; ++nt) {
      const int n = nbase + nt * 16 + l15;
      short8 bf = *(const short8*)(WbT + (size_t)n * C_ + k0);
      acc[nt] = __builtin_amdgcn_mfma_f32_16x16x32_bf16(af, bf, acc[nt], 0, 0, 0);
    }
  }

  // epilogue: D[row=quad*4+r][col=l15] per 16x16 tile
  const int row0 = m0 + quad * 4;
#pragma unroll
  for (int nt = 0; nt < 12; ++nt) {
    const int n = nbase + nt * 16;
    const int col = n + l15;
    if (n < 128) {
#pragma unroll
      for (int r = 0; r < 4; ++r)
        Qb[(size_t)(row0 + r) * H_ + col] = f2bf(acc[nt][r]);
    } else if (n < 256) {
#pragma unroll
      for (int r = 0; r < 4; ++r)
        Kb[(size_t)(row0 + r) * H_ + (col - 128)] = f2bf(acc[nt][r]);
    } else {
      const int h = col - 256;
      const int b = row0 >> 11;        // row0 / 2048
      const int t0 = row0 & 2047;      // multiple of 4 -> 8B aligned store
      ushort4v pk;
      pk[0] = f2bf(acc[nt][0]); pk[1] = f2bf(acc[nt][1]);
      pk[2] = f2bf(acc[nt][2]); pk[3] = f2bf(acc[nt][3]);
      *(ushort4v*)(VT + (size_t)(b * H_ + h) * T_ + t0) = pk;
    }
  }
}

// ---------------------------------------------------------------------------
// Kernel 3: flash attention. Block = (b, qtile of 32 rows), 4 waves.
// Each wave: all 32 q rows (2 MFMA m-tiles), KV tiles (32 wide) strided mod 4.
// Online softmax in fp32; P transits LDS (C-layout -> A-layout);
// K/V B-fragments loaded directly from global (Kb row-major, VT transposed).
// 4 partials combined via LDS at the end. out = fp32 [4][2048][128].
// ---------------------------------------------------------------------------
__global__ __launch_bounds__(256) void attn(const unsigned short* __restrict__ Qb,
                                            const unsigned short* __restrict__ Kb,
                                            const unsigned short* __restrict__ VT,
                                            float* __restrict__ out) {
  __shared__ unsigned short lds_p[4][32][32];    // per-wave P scratch (bf16)
  __shared__ unsigned short lds_O[4][32][128];   // per-wave partial O (bf16)
  __shared__ float lds_m[4][32];
  __shared__ float lds_l[4][32];

  const int tid  = threadIdx.x;
  const int wave = tid >> 6, lane = tid & 63;
  const int quad = lane >> 4, l15 = lane & 15;
  const int qt = blockIdx.x >> 2;
  const int b  = blockIdx.x & 3;
  const int Q0 = qt * 32;

  const unsigned short* Qbase = Qb + (size_t)(b * T_ + Q0) * H_;
  const unsigned short* Kbase = Kb + (size_t)(b * T_) * H_;
  const unsigned short* Vbase = VT + (size_t)(b * H_) * T_;

  // preload Q fragments: aq[mt][ks], A[m=l15][k=quad*8+j] at k-block ks*32
  short8 aq[2][4];
#pragma unroll
  for (int mt = 0; mt < 2; ++mt) {
    const unsigned short* qrow = Qbase + (size_t)(mt * 16 + l15) * H_;
#pragma unroll
    for (int ks = 0; ks < 4; ++ks)
      aq[mt][ks] = *(const short8*)(qrow + ks * 32 + quad * 8);
  }

  const f32x4 zero4 = {0.f, 0.f, 0.f, 0.f};
  f32x4 O[2][8];
#pragma unroll
  for (int mt = 0; mt < 2; ++mt)
#pragma unroll
    for (int nth = 0; nth < 8; ++nth) O[mt][nth] = zero4;
  float m_[2][4], l_[2][4];
#pragma unroll
  for (int mt = 0; mt < 2; ++mt)
#pragma unroll
    for (int r = 0; r < 4; ++r) { m_[mt][r] = NEG_BIG; l_[mt][r] = 0.f; }

  const float cS = 0.045084220027780106f;  // log2(e) / 32  (scale = C^-0.5)
  const int ntiles = qt + 1;

  for (int t = wave; t < ntiles; t += 4) {
    const int kv0 = t * 32;
    // ---- S = Q . K^T  (2 m-tiles x 2 n-tiles, 4 k-steps over H=128)
    f32x4 S[2][2];
    S[0][0] = zero4; S[0][1] = zero4; S[1][0] = zero4; S[1][1] = zero4;
#pragma unroll
    for (int ks = 0; ks < 4; ++ks) {
#pragma unroll
      for (int ntl = 0; ntl < 2; ++ntl) {
        short8 kf = *(const short8*)(Kbase + (size_t)(kv0 + ntl * 16 + l15) * H_ +
                                     ks * 32 + quad * 8);
        S[0][ntl] = __builtin_amdgcn_mfma_f32_16x16x32_bf16(aq[0][ks], kf, S[0][ntl], 0, 0, 0);
        S[1][ntl] = __builtin_amdgcn_mfma_f32_16x16x32_bf16(aq[1][ks], kf, S[1][ntl], 0, 0, 0);
      }
    }
    // scale into log2 domain
#pragma unroll
    for (int mt = 0; mt < 2; ++mt)
#pragma unroll
      for (int ntl = 0; ntl < 2; ++ntl)
#pragma unroll
        for (int r = 0; r < 4; ++r) S[mt][ntl][r] *= cS;
    // causal mask (only diagonal tile needs it)
    if (t == qt) {
#pragma unroll
      for (int mt = 0; mt < 2; ++mt)
#pragma unroll
        for (int ntl = 0; ntl < 2; ++ntl)
#pragma unroll
          for (int r = 0; r < 4; ++r) {
            const int ql = mt * 16 + quad * 4 + r;
            const int kl = ntl * 16 + l15;
            if (kl > ql) S[mt][ntl][r] = NEG_BIG;
          }
    }
    // ---- online softmax per m-tile
#pragma unroll
    for (int mt = 0; mt < 2; ++mt) {
      float alpha[4];
#pragma unroll
      for (int r = 0; r < 4; ++r) {
        float v = fmaxf(S[mt][0][r], S[mt][1][r]);
        v = fmaxf(v, __shfl_xor(v, 1));
        v = fmaxf(v, __shfl_xor(v, 2));
        v = fmaxf(v, __shfl_xor(v, 4));
        v = fmaxf(v, __shfl_xor(v, 8));
        const float mn = fmaxf(m_[mt][r], v);
        alpha[r] = __builtin_amdgcn_exp2f(m_[mt][r] - mn);
        m_[mt][r] = mn;
      }
#pragma unroll
      for (int r = 0; r < 4; ++r) {
        S[mt][0][r] = __builtin_amdgcn_exp2f(S[mt][0][r] - m_[mt][r]);
        S[mt][1][r] = __builtin_amdgcn_exp2f(S[mt][1][r] - m_[mt][r]);
        float s = S[mt][0][r] + S[mt][1][r];
        s += __shfl_xor(s, 1);
        s += __shfl_xor(s, 2);
        s += __shfl_xor(s, 4);
        s += __shfl_xor(s, 8);
        l_[mt][r] = l_[mt][r] * alpha[r] + s;
      }
      // write P (bf16) to per-wave LDS, C-layout positions
#pragma unroll
      for (int ntl = 0; ntl < 2; ++ntl)
#pragma unroll
        for (int r = 0; r < 4; ++r)
          lds_p[wave][mt * 16 + quad * 4 + r][ntl * 16 + l15] = f2bf(S[mt][ntl][r]);
      // rescale O by alpha (skip when wave-uniformly 1.0)
      const int ns = (alpha[0] == 1.f) & (alpha[1] == 1.f) &
                     (alpha[2] == 1.f) & (alpha[3] == 1.f);
      if (!__all(ns)) {
#pragma unroll
        for (int nth = 0; nth < 8; ++nth)
#pragma unroll
          for (int r = 0; r < 4; ++r) O[mt][nth][r] *= alpha[r];
      }
    }
    // ---- O += P . V   (A-frags from LDS, B-frags direct from VT)
    short8 ap0 = *(const short8*)(&lds_p[wave][l15][quad * 8]);
    short8 ap1 = *(const short8*)(&lds_p[wave][16 + l15][quad * 8]);
#pragma unroll
    for (int nth = 0; nth < 8; ++nth) {
      short8 vf = *(const short8*)(Vbase + (size_t)(nth * 16 + l15) * T_ +
                                   kv0 + quad * 8);
      O[0][nth] = __builtin_amdgcn_mfma_f32_16x16x32_bf16(ap0, vf, O[0][nth], 0, 0, 0);
      O[1][nth] = __builtin_amdgcn_mfma_f32_16x16x32_bf16(ap1, vf, O[1][nth], 0, 0, 0);
    }
  }

  // ---- write this wave's partial (m, l, O) to LDS
#pragma unroll
  for (int mt = 0; mt < 2; ++mt) {
    if (l15 == 0) {
#pragma unroll
      for (int r = 0; r < 4; ++r) {
        lds_m[wave][mt * 16 + quad * 4 + r] = m_[mt][r];
        lds_l[wave][mt * 16 + quad * 4 + r] = l_[mt][r];
      }
    }
#pragma unroll
    for (int nth = 0; nth < 8; ++nth)
#pragma unroll
      for (int r = 0; r < 4; ++r)
        lds_O[wave][mt * 16 + quad * 4 + r][nth * 16 + l15] = f2bf(O[mt][nth][r]);
  }
  __syncthreads();

  // ---- combine 4 KV-split partials; thread -> (row, 16-col chunk)
  const int row = tid >> 3;
  const int c0  = (tid & 7) * 16;
  float m_fin = NEG_BIG;
#pragma unroll
  for (int w = 0; w < 4; ++w) m_fin = fmaxf(m_fin, lds_m[w][row]);
  float l_fin = 0.f;
  float o[16];
#pragma unroll
  for (int c = 0; c < 16; ++c) o[c] = 0.f;
#pragma unroll
  for (int w = 0; w < 4; ++w) {
    const float sc = __builtin_amdgcn_exp2f(lds_m[w][row] - m_fin);
    l_fin += sc * lds_l[w][row];
#pragma unroll
    for (int c = 0; c < 16; ++c)
      o[c] += sc * bf2f(lds_O[w][row][c0 + c]);
  }
  const float inv = 1.0f / l_fin;
  float* op = out + (size_t)(b * T_ + Q0 + row) * H_ + c0;
#pragma unroll
  for (int c = 0; c < 16; ++c) op[c] = o[c] * inv;
}

// ---------------------------------------------------------------------------
extern "C" void kernel_launch(void* const* d_in, const int* in_sizes, int n_in,
                              void* d_out, int out_size, void* d_ws, size_t ws_size,
                              hipStream_t stream) {
  const float* x  = (const float*)d_in[0];
  const float* Wq = (const float*)d_in[1];
  const float* Wk = (const float*)d_in[2];
  const float* Wv = (const float*)d_in[3];
  float* out = (float*)d_out;

  char* ws = (char*)d_ws;
  unsigned short* WbT = (unsigned short*)(ws);             // 384*1024*2   = 786432 B
  unsigned short* Qb  = (unsigned short*)(ws + 786432);    // 8192*128*2   = 2097152 B
  unsigned short* Kb  = (unsigned short*)(ws + 2883584);   // 8192*128*2
  unsigned short* VT  = (unsigned short*)(ws + 4980736);   // 4*128*2048*2

  prep_w<<<dim3(1536), dim3(256), 0, stream>>>(Wq, Wk, Wv, WbT);
  qkv_proj<<<dim3(256), dim3(256), 0, stream>>>(x, WbT, Qb, Kb, VT);
  attn<<<dim3(256), dim3(256), 0, stream>>>(Qb, Kb, VT, out);
}

// Round 2
// 172.822 us; speedup vs baseline: 1.3373x; 1.3373x over previous
//
#include <hip/hip_runtime.h>
#include <stdint.h>

#define B_ 4
#define T_ 2048
#define C_ 1024
#define H_ 128
#define NEG_BIG -3.0e38f

typedef __attribute__((ext_vector_type(8))) short short8;
typedef __attribute__((ext_vector_type(4))) float f32x4;
typedef __attribute__((ext_vector_type(4))) unsigned short ushort4v;

__device__ __forceinline__ unsigned short f2bf(float f) {
  union { float f; unsigned u; } cv; cv.f = f;
  unsigned u = cv.u;
  return (unsigned short)((u + 0x7fffu + ((u >> 16) & 1u)) >> 16);  // RNE
}

__device__ __forceinline__ float bf2f(unsigned short s) {
  union { unsigned u; float f; } cv; cv.u = ((unsigned)s) << 16;
  return cv.f;
}

// ---------------------------------------------------------------------------
// Kernel 1: prep — cast x (fp32 [8192][1024]) to xb bf16 row-major, and
// Wq|Wk|Wv (fp32 [1024][128]) to WbT bf16 [384][1024] (transposed).
// Memory-bound: ~48 MB total traffic.
// ---------------------------------------------------------------------------
__global__ __launch_bounds__(256) void prep(const float* __restrict__ x,
                                            const float* __restrict__ Wq,
                                            const float* __restrict__ Wk,
                                            const float* __restrict__ Wv,
                                            unsigned short* __restrict__ xb,
                                            unsigned short* __restrict__ WbT) {
  if (blockIdx.x < 8192) {
    const int base = (blockIdx.x * 256 + threadIdx.x) * 4;  // < 8388608
    f32x4 v = *(const f32x4*)(x + base);
    ushort4v p;
    p[0] = f2bf(v[0]); p[1] = f2bf(v[1]); p[2] = f2bf(v[2]); p[3] = f2bf(v[3]);
    *(ushort4v*)(xb + base) = p;
  } else {
    const int i = (blockIdx.x - 8192) * 256 + threadIdx.x;  // 0..98303
    const int linear = i * 4;                               // < 393216
    const int j = linear >> 10;                             // output row 0..383
    const int k0 = linear & 1023;
    const float* W = (j < 128) ? Wq : (j < 256) ? Wk : Wv;
    const int h = j & 127;
    ushort4v p;
    p[0] = f2bf(W[(k0 + 0) * 128 + h]);
    p[1] = f2bf(W[(k0 + 1) * 128 + h]);
    p[2] = f2bf(W[(k0 + 2) * 128 + h]);
    p[3] = f2bf(W[(k0 + 3) * 128 + h]);
    *(ushort4v*)(WbT + linear) = p;
  }
}

// ---------------------------------------------------------------------------
// Kernel 2: QKV projection, pure-bf16 direct-fragment GEMM.
// Wave = 16 rows x 96 cols (6 acc tiles); block = 4 waves stacked in M
// (64 rows x 96 cols). Grid = 128 row-blocks x 4 col-blocks = 512 blocks
// -> 2 blocks/CU, 8 waves/CU.  A-frags: contiguous 16B loads from xb;
// B-frags: contiguous 16B loads from WbT (L1/L2 resident).
// Writes Qb[8192][128], Kb[8192][128], VT[4][128][2048] (V transposed).
// ---------------------------------------------------------------------------
__global__ __launch_bounds__(256) void qkv_proj(const unsigned short* __restrict__ xb,
                                                const unsigned short* __restrict__ WbT,
                                                unsigned short* __restrict__ Qb,
                                                unsigned short* __restrict__ Kb,
                                                unsigned short* __restrict__ VT) {
  const int tid  = threadIdx.x;
  const int wave = tid >> 6, lane = tid & 63;
  const int quad = lane >> 4, l15 = lane & 15;
  const int rb = blockIdx.x >> 2, cb = blockIdx.x & 3;
  const int m0 = rb * 64 + wave * 16;
  const int nbase = cb * 96;

  f32x4 acc[6];
  const f32x4 zero4 = {0.f, 0.f, 0.f, 0.f};
#pragma unroll
  for (int i = 0; i < 6; ++i) acc[i] = zero4;

  const unsigned short* xrow = xb + (size_t)(m0 + l15) * C_;
  const unsigned short* wbase = WbT + (size_t)(nbase + l15) * C_;

#pragma unroll 2
  for (int ks = 0; ks < 32; ++ks) {
    const int k0 = ks * 32 + quad * 8;
    short8 af = *(const short8*)(xrow + k0);
#pragma unroll
    for (int nt = 0; nt < 6; ++nt) {
      short8 bf = *(const short8*)(wbase + (size_t)(nt * 16) * C_ + k0);
      acc[nt] = __builtin_amdgcn_mfma_f32_16x16x32_bf16(af, bf, acc[nt], 0, 0, 0);
    }
  }

  // epilogue: D[row=quad*4+r][col=l15] per 16x16 tile
  const int row0 = m0 + quad * 4;
#pragma unroll
  for (int nt = 0; nt < 6; ++nt) {
    const int n = nbase + nt * 16;
    const int col = n + l15;
    if (n < 128) {
#pragma unroll
      for (int r = 0; r < 4; ++r)
        Qb[(size_t)(row0 + r) * H_ + col] = f2bf(acc[nt][r]);
    } else if (n < 256) {
#pragma unroll
      for (int r = 0; r < 4; ++r)
        Kb[(size_t)(row0 + r) * H_ + (col - 128)] = f2bf(acc[nt][r]);
    } else {
      const int h = col - 256;
      const int b = row0 >> 11;
      const int t0 = row0 & 2047;  // multiple of 4 -> 8B aligned store
      ushort4v pk;
      pk[0] = f2bf(acc[nt][0]); pk[1] = f2bf(acc[nt][1]);
      pk[2] = f2bf(acc[nt][2]); pk[3] = f2bf(acc[nt][3]);
      *(ushort4v*)(VT + (size_t)(b * H_ + h) * T_ + t0) = pk;
    }
  }
}

// ---------------------------------------------------------------------------
// Kernel 3: flash attention. Block = (b, qtile of 32 rows), 8 waves (512 thr).
// Each wave: all 32 q rows (2 MFMA m-tiles), KV tiles (32 wide) strided mod 8.
// K-fragments for the NEXT tile are prefetched before the softmax VALU section
// to hide load latency. Online softmax in fp32; P transits per-wave LDS
// (C-layout -> A-layout). 8 partials combined via LDS. out fp32 [4][2048][128].
// ---------------------------------------------------------------------------
__global__ __launch_bounds__(512, 2) void attn(const unsigned short* __restrict__ Qb,
                                               const unsigned short* __restrict__ Kb,
                                               const unsigned short* __restrict__ VT,
                                               float* __restrict__ out) {
  __shared__ unsigned short lds_p[8][32][32];    // per-wave P scratch (bf16)
  __shared__ unsigned short lds_O[8][32][128];   // per-wave partial O (bf16)
  __shared__ float lds_m[8][32];
  __shared__ float lds_l[8][32];

  const int tid  = threadIdx.x;
  const int wave = tid >> 6, lane = tid & 63;
  const int quad = lane >> 4, l15 = lane & 15;
  const int qt = blockIdx.x >> 2;
  const int b  = blockIdx.x & 3;
  const int Q0 = qt * 32;

  const unsigned short* Qbase = Qb + (size_t)(b * T_ + Q0) * H_;
  const unsigned short* Kbase = Kb + (size_t)(b * T_) * H_;
  const unsigned short* Vbase = VT + (size_t)(b * H_) * T_;

  // preload Q fragments: aq[mt][ks], A[m=l15][k=quad*8+j] at k-block ks*32
  short8 aq[2][4];
#pragma unroll
  for (int mt = 0; mt < 2; ++mt) {
    const unsigned short* qrow = Qbase + (size_t)(mt * 16 + l15) * H_;
#pragma unroll
    for (int ks = 0; ks < 4; ++ks)
      aq[mt][ks] = *(const short8*)(qrow + ks * 32 + quad * 8);
  }

  const f32x4 zero4 = {0.f, 0.f, 0.f, 0.f};
  f32x4 O[2][8];
#pragma unroll
  for (int mt = 0; mt < 2; ++mt)
#pragma unroll
    for (int nth = 0; nth < 8; ++nth) O[mt][nth] = zero4;
  float m_[2][4], l_[2][4];
#pragma unroll
  for (int mt = 0; mt < 2; ++mt)
#pragma unroll
    for (int r = 0; r < 4; ++r) { m_[mt][r] = NEG_BIG; l_[mt][r] = 0.f; }

  const float cS = 0.045084220027780106f;  // log2(e) / 32  (scale = C^-0.5)
  const int ntiles = qt + 1;

  int t = wave;
  short8 kf[2][4];  // [ntl][ks]
  if (t < ntiles) {
    const int kv0 = t * 32;
#pragma unroll
    for (int ntl = 0; ntl < 2; ++ntl)
#pragma unroll
      for (int ks = 0; ks < 4; ++ks)
        kf[ntl][ks] = *(const short8*)(Kbase + (size_t)(kv0 + ntl * 16 + l15) * H_ +
                                       ks * 32 + quad * 8);
  }

  while (t < ntiles) {
    const int kv0 = t * 32;
    // ---- S = Q . K^T  (2 m-tiles x 2 n-tiles, 4 k-steps over H=128)
    f32x4 S[2][2];
    S[0][0] = zero4; S[0][1] = zero4; S[1][0] = zero4; S[1][1] = zero4;
#pragma unroll
    for (int ks = 0; ks < 4; ++ks)
#pragma unroll
      for (int ntl = 0; ntl < 2; ++ntl) {
        S[0][ntl] = __builtin_amdgcn_mfma_f32_16x16x32_bf16(aq[0][ks], kf[ntl][ks], S[0][ntl], 0, 0, 0);
        S[1][ntl] = __builtin_amdgcn_mfma_f32_16x16x32_bf16(aq[1][ks], kf[ntl][ks], S[1][ntl], 0, 0, 0);
      }

    // ---- prefetch next KV tile's K-fragments (hides latency under softmax)
    const int tn = t + 8;
    short8 kfn[2][4];
    if (tn < ntiles) {
      const int kv0n = tn * 32;
#pragma unroll
      for (int ntl = 0; ntl < 2; ++ntl)
#pragma unroll
        for (int ks = 0; ks < 4; ++ks)
          kfn[ntl][ks] = *(const short8*)(Kbase + (size_t)(kv0n + ntl * 16 + l15) * H_ +
                                          ks * 32 + quad * 8);
    }

    // scale into log2 domain
#pragma unroll
    for (int mt = 0; mt < 2; ++mt)
#pragma unroll
      for (int ntl = 0; ntl < 2; ++ntl)
#pragma unroll
        for (int r = 0; r < 4; ++r) S[mt][ntl][r] *= cS;
    // causal mask (only diagonal tile needs it)
    if (t == qt) {
#pragma unroll
      for (int mt = 0; mt < 2; ++mt)
#pragma unroll
        for (int ntl = 0; ntl < 2; ++ntl)
#pragma unroll
          for (int r = 0; r < 4; ++r) {
            const int ql = mt * 16 + quad * 4 + r;
            const int kl = ntl * 16 + l15;
            if (kl > ql) S[mt][ntl][r] = NEG_BIG;
          }
    }
    // ---- online softmax per m-tile
#pragma unroll
    for (int mt = 0; mt < 2; ++mt) {
      float alpha[4];
#pragma unroll
      for (int r = 0; r < 4; ++r) {
        float v = fmaxf(S[mt][0][r], S[mt][1][r]);
        v = fmaxf(v, __shfl_xor(v, 1));
        v = fmaxf(v, __shfl_xor(v, 2));
        v = fmaxf(v, __shfl_xor(v, 4));
        v = fmaxf(v, __shfl_xor(v, 8));
        const float mn = fmaxf(m_[mt][r], v);
        alpha[r] = __builtin_amdgcn_exp2f(m_[mt][r] - mn);
        m_[mt][r] = mn;
      }
#pragma unroll
      for (int r = 0; r < 4; ++r) {
        S[mt][0][r] = __builtin_amdgcn_exp2f(S[mt][0][r] - m_[mt][r]);
        S[mt][1][r] = __builtin_amdgcn_exp2f(S[mt][1][r] - m_[mt][r]);
        float s = S[mt][0][r] + S[mt][1][r];
        s += __shfl_xor(s, 1);
        s += __shfl_xor(s, 2);
        s += __shfl_xor(s, 4);
        s += __shfl_xor(s, 8);
        l_[mt][r] = l_[mt][r] * alpha[r] + s;
      }
      // write P (bf16) to per-wave LDS, C-layout positions
#pragma unroll
      for (int ntl = 0; ntl < 2; ++ntl)
#pragma unroll
        for (int r = 0; r < 4; ++r)
          lds_p[wave][mt * 16 + quad * 4 + r][ntl * 16 + l15] = f2bf(S[mt][ntl][r]);
      // rescale O by alpha (skip when wave-uniformly 1.0)
      const int ns = (alpha[0] == 1.f) & (alpha[1] == 1.f) &
                     (alpha[2] == 1.f) & (alpha[3] == 1.f);
      if (!__all(ns)) {
#pragma unroll
        for (int nth = 0; nth < 8; ++nth)
#pragma unroll
          for (int r = 0; r < 4; ++r) O[mt][nth][r] *= alpha[r];
      }
    }
    // ---- O += P . V   (A-frags from LDS, B-frags direct from VT)
    short8 ap0 = *(const short8*)(&lds_p[wave][l15][quad * 8]);
    short8 ap1 = *(const short8*)(&lds_p[wave][16 + l15][quad * 8]);
#pragma unroll
    for (int nth = 0; nth < 8; ++nth) {
      short8 vf = *(const short8*)(Vbase + (size_t)(nth * 16 + l15) * T_ +
                                   kv0 + quad * 8);
      O[0][nth] = __builtin_amdgcn_mfma_f32_16x16x32_bf16(ap0, vf, O[0][nth], 0, 0, 0);
      O[1][nth] = __builtin_amdgcn_mfma_f32_16x16x32_bf16(ap1, vf, O[1][nth], 0, 0, 0);
    }
    // advance
#pragma unroll
    for (int ntl = 0; ntl < 2; ++ntl)
#pragma unroll
      for (int ks = 0; ks < 4; ++ks) kf[ntl][ks] = kfn[ntl][ks];
    t = tn;
  }

  // ---- write this wave's partial (m, l, O) to LDS
#pragma unroll
  for (int mt = 0; mt < 2; ++mt) {
    if (l15 == 0) {
#pragma unroll
      for (int r = 0; r < 4; ++r) {
        lds_m[wave][mt * 16 + quad * 4 + r] = m_[mt][r];
        lds_l[wave][mt * 16 + quad * 4 + r] = l_[mt][r];
      }
    }
#pragma unroll
    for (int nth = 0; nth < 8; ++nth)
#pragma unroll
      for (int r = 0; r < 4; ++r)
        lds_O[wave][mt * 16 + quad * 4 + r][nth * 16 + l15] = f2bf(O[mt][nth][r]);
  }
  __syncthreads();

  // ---- combine 8 KV-split partials; thread -> (row, 8-col chunk)
  const int row = tid >> 4;
  const int c0  = (tid & 15) * 8;
  float m_fin = NEG_BIG;
#pragma unroll
  for (int w = 0; w < 8; ++w) m_fin = fmaxf(m_fin, lds_m[w][row]);
  float l_fin = 0.f;
  float o[8];
#pragma unroll
  for (int c = 0; c < 8; ++c) o[c] = 0.f;
#pragma unroll
  for (int w = 0; w < 8; ++w) {
    const float sc = __builtin_amdgcn_exp2f(lds_m[w][row] - m_fin);
    l_fin += sc * lds_l[w][row];
#pragma unroll
    for (int c = 0; c < 8; ++c)
      o[c] += sc * bf2f(lds_O[w][row][c0 + c]);
  }
  const float inv = 1.0f / l_fin;
  float* op = out + (size_t)(b * T_ + Q0 + row) * H_ + c0;
#pragma unroll
  for (int c = 0; c < 8; ++c) op[c] = o[c] * inv;
}

// ---------------------------------------------------------------------------
extern "C" void kernel_launch(void* const* d_in, const int* in_sizes, int n_in,
                              void* d_out, int out_size, void* d_ws, size_t ws_size,
                              hipStream_t stream) {
  const float* x  = (const float*)d_in[0];
  const float* Wq = (const float*)d_in[1];
  const float* Wk = (const float*)d_in[2];
  const float* Wv = (const float*)d_in[3];
  float* out = (float*)d_out;

  char* ws = (char*)d_ws;
  unsigned short* xb  = (unsigned short*)(ws);              // 8192*1024*2 = 16777216 B
  unsigned short* WbT = (unsigned short*)(ws + 16777216);   // 384*1024*2  =   786432 B
  unsigned short* Qb  = (unsigned short*)(ws + 17563648);   // 8192*128*2  =  2097152 B
  unsigned short* Kb  = (unsigned short*)(ws + 19660800);   // 8192*128*2
  unsigned short* VT  = (unsigned short*)(ws + 21757952);   // 4*128*2048*2

  prep<<<dim3(8576), dim3(256), 0, stream>>>(x, Wq, Wk, Wv, xb, WbT);
  qkv_proj<<<dim3(512), dim3(256), 0, stream>>>(xb, WbT, Qb, Kb, VT);
  attn<<<dim3(256), dim3(512), 0, stream>>>(Qb, Kb, VT, out);
}

// Round 3
// 147.129 us; speedup vs baseline: 1.5708x; 1.1746x over previous
//
#include <hip/hip_runtime.h>
#include <stdint.h>

#define B_ 4
#define T_ 2048
#define C_ 1024
#define H_ 128
#define NEG_BIG -3.0e38f

typedef __attribute__((ext_vector_type(8))) short short8;
typedef __attribute__((ext_vector_type(4))) float f32x4;
typedef __attribute__((ext_vector_type(4))) unsigned short ushort4v;
typedef __attribute__((ext_vector_type(8))) unsigned short ushort8v;

__device__ __forceinline__ unsigned short f2bf(float f) {
  union { float f; unsigned u; } cv; cv.f = f;
  unsigned u = cv.u;
  return (unsigned short)((u + 0x7fffu + ((u >> 16) & 1u)) >> 16);  // RNE
}

__device__ __forceinline__ float bf2f(unsigned short s) {
  union { unsigned u; float f; } cv; cv.u = ((unsigned)s) << 16;
  return cv.f;
}

// async global->LDS, 16 bytes per lane. LDS dest = wave-uniform base + lane*16.
__device__ __forceinline__ void gld16(const unsigned short* g, unsigned short* l) {
  __builtin_amdgcn_global_load_lds(
      (const __attribute__((address_space(1))) unsigned int*)g,
      (__attribute__((address_space(3))) unsigned int*)l, 16, 0, 0);
}

// scale = C^-0.5 = 1/32; folded with log2(e) for exp2-domain softmax
#define CSCALE 0.045084220027780106f

// ---------------------------------------------------------------------------
// Kernel 1: prep — cast x (fp32 [8192][1024]) to xb bf16, and Wq|Wk|Wv
// (fp32 [1024][128]) to WbT bf16 [384][1024] (transposed). Memory-bound.
// ---------------------------------------------------------------------------
__global__ __launch_bounds__(256) void prep(const float* __restrict__ x,
                                            const float* __restrict__ Wq,
                                            const float* __restrict__ Wk,
                                            const float* __restrict__ Wv,
                                            unsigned short* __restrict__ xb,
                                            unsigned short* __restrict__ WbT) {
  if (blockIdx.x < 8192) {
    const int base = (blockIdx.x * 256 + threadIdx.x) * 4;
    f32x4 v = *(const f32x4*)(x + base);
    ushort4v p;
    p[0] = f2bf(v[0]); p[1] = f2bf(v[1]); p[2] = f2bf(v[2]); p[3] = f2bf(v[3]);
    *(ushort4v*)(xb + base) = p;
  } else {
    const int i = (blockIdx.x - 8192) * 256 + threadIdx.x;  // 0..98303
    const int linear = i * 4;
    const int j = linear >> 10;
    const int k0 = linear & 1023;
    const float* W = (j < 128) ? Wq : (j < 256) ? Wk : Wv;
    const int h = j & 127;
    ushort4v p;
    p[0] = f2bf(W[(k0 + 0) * 128 + h]);
    p[1] = f2bf(W[(k0 + 1) * 128 + h]);
    p[2] = f2bf(W[(k0 + 2) * 128 + h]);
    p[3] = f2bf(W[(k0 + 3) * 128 + h]);
    *(ushort4v*)(WbT + linear) = p;
  }
}

// ---------------------------------------------------------------------------
// Kernel 2: QKV projection — m97-style LDS GEMM.
// Tile 64M x 96N x 32K; grid = 128 rb x 4 cb = 512 blocks (2/CU), 256 thr.
// Waves 2x2; wave computes 32x48 (2 mt x 3 nt accs).
// Staging via global_load_lds(16B). LDS layout XOR-swizzled on the global
// source side: row r's k-chunk q lives at slot p = (q + r + (r>>2)) & 3,
// making ds_read_b128 <=2-way bank-conflicted (free).
// Q written pre-scaled by CSCALE. V written transposed (VT[b][h][t]).
// ---------------------------------------------------------------------------
__global__ __launch_bounds__(256) void qkv_proj(const unsigned short* __restrict__ xb,
                                                const unsigned short* __restrict__ WbT,
                                                unsigned short* __restrict__ Qb,
                                                unsigned short* __restrict__ Kb,
                                                unsigned short* __restrict__ VT) {
  __shared__ unsigned short As[64 * 32];   // 4 KB
  __shared__ unsigned short Bs[96 * 32];   // 6 KB

  const int tid  = threadIdx.x;
  const int wave = tid >> 6, lane = tid & 63;
  const int quad = lane >> 4, l15 = lane & 15;
  const int rb = blockIdx.x >> 2, cb = blockIdx.x & 3;
  const int gm0 = rb * 64, gn0 = cb * 96;
  const int wm = wave >> 1, wn = wave & 1;

  // staging source/dest (per-thread, fixed across k-iters up to +ko)
  const int ra = tid >> 2, pa = tid & 3;
  const int ca = (pa - ra - (ra >> 2)) & 3;                  // global chunk for slot pa
  const unsigned short* gA = xb + (size_t)(gm0 + ra) * C_ + ca * 8;
  unsigned short* lA = As + tid * 8;
  const unsigned short* gB0 = WbT + (size_t)(gn0 + ra) * C_ + ca * 8;
  unsigned short* lB0 = Bs + tid * 8;
  const int rb2 = 64 + ra;                                   // rows 64..95 (waves 0,1)
  const int cb2 = (pa - rb2 - (rb2 >> 2)) & 3;
  const unsigned short* gB2 = WbT + (size_t)(gn0 + rb2) * C_ + cb2 * 8;
  unsigned short* lB2 = Bs + 64 * 32 + tid * 8;

  // fragment read offsets (elements)
  int aoff[2], boff[3];
#pragma unroll
  for (int mt = 0; mt < 2; ++mt) {
    const int r = wm * 32 + mt * 16 + l15;
    aoff[mt] = r * 32 + ((quad + r + (r >> 2)) & 3) * 8;
  }
#pragma unroll
  for (int nt = 0; nt < 3; ++nt) {
    const int r = wn * 48 + nt * 16 + l15;
    boff[nt] = r * 32 + ((quad + r + (r >> 2)) & 3) * 8;
  }

  f32x4 acc[2][3];
  const f32x4 zero4 = {0.f, 0.f, 0.f, 0.f};
#pragma unroll
  for (int mt = 0; mt < 2; ++mt)
#pragma unroll
    for (int nt = 0; nt < 3; ++nt) acc[mt][nt] = zero4;

  for (int kb = 0; kb < 32; ++kb) {
    const int ko = kb * 32;
    if (kb) __syncthreads();          // previous reads complete before overwrite
    gld16(gA + ko, lA);
    gld16(gB0 + ko, lB0);
    if (wave < 2) gld16(gB2 + ko, lB2);
    __syncthreads();                  // vmcnt(0) drained by barrier -> staged visible

    short8 a0 = *(const short8*)(As + aoff[0]);
    short8 a1 = *(const short8*)(As + aoff[1]);
    short8 b0 = *(const short8*)(Bs + boff[0]);
    short8 b1 = *(const short8*)(Bs + boff[1]);
    short8 b2 = *(const short8*)(Bs + boff[2]);
    acc[0][0] = __builtin_amdgcn_mfma_f32_16x16x32_bf16(a0, b0, acc[0][0], 0, 0, 0);
    acc[0][1] = __builtin_amdgcn_mfma_f32_16x16x32_bf16(a0, b1, acc[0][1], 0, 0, 0);
    acc[0][2] = __builtin_amdgcn_mfma_f32_16x16x32_bf16(a0, b2, acc[0][2], 0, 0, 0);
    acc[1][0] = __builtin_amdgcn_mfma_f32_16x16x32_bf16(a1, b0, acc[1][0], 0, 0, 0);
    acc[1][1] = __builtin_amdgcn_mfma_f32_16x16x32_bf16(a1, b1, acc[1][1], 0, 0, 0);
    acc[1][2] = __builtin_amdgcn_mfma_f32_16x16x32_bf16(a1, b2, acc[1][2], 0, 0, 0);
  }

  // epilogue: D[row=quad*4+r][col=l15] per 16x16 tile
#pragma unroll
  for (int mt = 0; mt < 2; ++mt) {
    const int row0 = gm0 + wm * 32 + mt * 16 + quad * 4;
#pragma unroll
    for (int nt = 0; nt < 3; ++nt) {
      const int colbase = gn0 + wn * 48 + nt * 16;   // multiple of 16
      const int col = colbase + l15;
      if (colbase < 128) {          // Q (pre-scaled)
#pragma unroll
        for (int r = 0; r < 4; ++r)
          Qb[(size_t)(row0 + r) * H_ + col] = f2bf(acc[mt][nt][r] * CSCALE);
      } else if (colbase < 256) {   // K
#pragma unroll
        for (int r = 0; r < 4; ++r)
          Kb[(size_t)(row0 + r) * H_ + (col - 128)] = f2bf(acc[mt][nt][r]);
      } else {                      // V, transposed
        const int h = col - 256;
        const int bidx = row0 >> 11;
        const int t0 = row0 & 2047;
        ushort4v pk;
        pk[0] = f2bf(acc[mt][nt][0]); pk[1] = f2bf(acc[mt][nt][1]);
        pk[2] = f2bf(acc[mt][nt][2]); pk[3] = f2bf(acc[mt][nt][3]);
        *(ushort4v*)(VT + (size_t)(bidx * H_ + h) * T_ + t0) = pk;
      }
    }
  }
}

// ---------------------------------------------------------------------------
// Kernel 3: flash attention stage 1, uniform-work split-KV.
// Grid 1024: b = bid&3, qt = (bid>>2)&63, ch = bid>>8 (16 KV tiles per chunk).
// Invalid chunks (ch*16 > qt) exit. 4 waves stride the chunk's tiles.
// Partial (O bf16 un-normalized, m, l) -> ws;  qt<16 writes out directly.
// ---------------------------------------------------------------------------
__global__ __launch_bounds__(256) void attn1(const unsigned short* __restrict__ Qb,
                                             const unsigned short* __restrict__ Kb,
                                             const unsigned short* __restrict__ VT,
                                             unsigned short* __restrict__ Opart,
                                             float* __restrict__ mpart,
                                             float* __restrict__ lpart,
                                             float* __restrict__ out) {
  const int bid = blockIdx.x;
  const int b  = bid & 3;
  const int qt = (bid >> 2) & 63;
  const int ch = bid >> 8;
  const int first = ch * 16;
  if (first > qt) return;
  const int last = min(qt, first + 15);

  __shared__ unsigned short lds_p[4][32][32];
  __shared__ unsigned short lds_O[4][32][128];
  __shared__ float lds_m[4][32];
  __shared__ float lds_l[4][32];

  const int tid  = threadIdx.x;
  const int wave = tid >> 6, lane = tid & 63;
  const int quad = lane >> 4, l15 = lane & 15;
  const int Q0 = qt * 32;

  const unsigned short* Qbase = Qb + (size_t)(b * T_ + Q0) * H_;
  const unsigned short* Kbase = Kb + (size_t)(b * T_) * H_;
  const unsigned short* Vbase = VT + (size_t)(b * H_) * T_;

  short8 aq[2][4];
#pragma unroll
  for (int mt = 0; mt < 2; ++mt) {
    const unsigned short* qrow = Qbase + (size_t)(mt * 16 + l15) * H_;
#pragma unroll
    for (int ks = 0; ks < 4; ++ks)
      aq[mt][ks] = *(const short8*)(qrow + ks * 32 + quad * 8);
  }

  const f32x4 zero4 = {0.f, 0.f, 0.f, 0.f};
  f32x4 O[2][8];
#pragma unroll
  for (int mt = 0; mt < 2; ++mt)
#pragma unroll
    for (int nth = 0; nth < 8; ++nth) O[mt][nth] = zero4;
  float m_[2][4], l_[2][4];
#pragma unroll
  for (int mt = 0; mt < 2; ++mt)
#pragma unroll
    for (int r = 0; r < 4; ++r) { m_[mt][r] = NEG_BIG; l_[mt][r] = 0.f; }

  for (int t = first + wave; t <= last; t += 4) {
    const int kv0 = t * 32;
    f32x4 S[2][2];
    S[0][0] = zero4; S[0][1] = zero4; S[1][0] = zero4; S[1][1] = zero4;
#pragma unroll
    for (int ks = 0; ks < 4; ++ks)
#pragma unroll
      for (int ntl = 0; ntl < 2; ++ntl) {
        short8 kf = *(const short8*)(Kbase + (size_t)(kv0 + ntl * 16 + l15) * H_ +
                                     ks * 32 + quad * 8);
        S[0][ntl] = __builtin_amdgcn_mfma_f32_16x16x32_bf16(aq[0][ks], kf, S[0][ntl], 0, 0, 0);
        S[1][ntl] = __builtin_amdgcn_mfma_f32_16x16x32_bf16(aq[1][ks], kf, S[1][ntl], 0, 0, 0);
      }
    if (t == qt) {  // causal mask on diagonal tile (Q pre-scaled, S in log2 dom)
#pragma unroll
      for (int mt = 0; mt < 2; ++mt)
#pragma unroll
        for (int ntl = 0; ntl < 2; ++ntl)
#pragma unroll
          for (int r = 0; r < 4; ++r) {
            const int ql = mt * 16 + quad * 4 + r;
            const int kl = ntl * 16 + l15;
            if (kl > ql) S[mt][ntl][r] = NEG_BIG;
          }
    }
#pragma unroll
    for (int mt = 0; mt < 2; ++mt) {
      float alpha[4];
#pragma unroll
      for (int r = 0; r < 4; ++r) {
        float v = fmaxf(S[mt][0][r], S[mt][1][r]);
        v = fmaxf(v, __shfl_xor(v, 1));
        v = fmaxf(v, __shfl_xor(v, 2));
        v = fmaxf(v, __shfl_xor(v, 4));
        v = fmaxf(v, __shfl_xor(v, 8));
        const float mn = fmaxf(m_[mt][r], v);
        alpha[r] = __builtin_amdgcn_exp2f(m_[mt][r] - mn);
        m_[mt][r] = mn;
      }
#pragma unroll
      for (int r = 0; r < 4; ++r) {
        S[mt][0][r] = __builtin_amdgcn_exp2f(S[mt][0][r] - m_[mt][r]);
        S[mt][1][r] = __builtin_amdgcn_exp2f(S[mt][1][r] - m_[mt][r]);
        float s = S[mt][0][r] + S[mt][1][r];
        s += __shfl_xor(s, 1);
        s += __shfl_xor(s, 2);
        s += __shfl_xor(s, 4);
        s += __shfl_xor(s, 8);
        l_[mt][r] = l_[mt][r] * alpha[r] + s;
      }
#pragma unroll
      for (int ntl = 0; ntl < 2; ++ntl)
#pragma unroll
        for (int r = 0; r < 4; ++r)
          lds_p[wave][mt * 16 + quad * 4 + r][ntl * 16 + l15] = f2bf(S[mt][ntl][r]);
      const int ns = (alpha[0] == 1.f) & (alpha[1] == 1.f) &
                     (alpha[2] == 1.f) & (alpha[3] == 1.f);
      if (!__all(ns)) {
#pragma unroll
        for (int nth = 0; nth < 8; ++nth)
#pragma unroll
          for (int r = 0; r < 4; ++r) O[mt][nth][r] *= alpha[r];
      }
    }
    short8 ap0 = *(const short8*)(&lds_p[wave][l15][quad * 8]);
    short8 ap1 = *(const short8*)(&lds_p[wave][16 + l15][quad * 8]);
#pragma unroll
    for (int nth = 0; nth < 8; ++nth) {
      short8 vf = *(const short8*)(Vbase + (size_t)(nth * 16 + l15) * T_ +
                                   kv0 + quad * 8);
      O[0][nth] = __builtin_amdgcn_mfma_f32_16x16x32_bf16(ap0, vf, O[0][nth], 0, 0, 0);
      O[1][nth] = __builtin_amdgcn_mfma_f32_16x16x32_bf16(ap1, vf, O[1][nth], 0, 0, 0);
    }
  }

  // per-wave partial -> LDS
#pragma unroll
  for (int mt = 0; mt < 2; ++mt) {
    if (l15 == 0) {
#pragma unroll
      for (int r = 0; r < 4; ++r) {
        lds_m[wave][mt * 16 + quad * 4 + r] = m_[mt][r];
        lds_l[wave][mt * 16 + quad * 4 + r] = l_[mt][r];
      }
    }
#pragma unroll
    for (int nth = 0; nth < 8; ++nth)
#pragma unroll
      for (int r = 0; r < 4; ++r)
        lds_O[wave][mt * 16 + quad * 4 + r][nth * 16 + l15] = f2bf(O[mt][nth][r]);
  }
  __syncthreads();

  // combine 4 waves: thread -> (row, 16-col chunk)
  const int row = tid >> 3;
  const int c0  = (tid & 7) * 16;
  float m_fin = NEG_BIG;
#pragma unroll
  for (int w = 0; w < 4; ++w) m_fin = fmaxf(m_fin, lds_m[w][row]);
  float l_fin = 0.f;
  float o[16];
#pragma unroll
  for (int c = 0; c < 16; ++c) o[c] = 0.f;
#pragma unroll
  for (int w = 0; w < 4; ++w) {
    const float sc = __builtin_amdgcn_exp2f(lds_m[w][row] - m_fin);
    l_fin += sc * lds_l[w][row];
#pragma unroll
    for (int c = 0; c < 16; ++c)
      o[c] += sc * bf2f(lds_O[w][row][c0 + c]);
  }

  if (qt < 16) {  // single chunk -> final output
    const float inv = 1.0f / l_fin;
    float* op = out + (size_t)(b * T_ + Q0 + row) * H_ + c0;
#pragma unroll
    for (int c = 0; c < 16; c += 4) {
      f32x4 v = {o[c] * inv, o[c + 1] * inv, o[c + 2] * inv, o[c + 3] * inv};
      *(f32x4*)(op + c) = v;
    }
  } else {        // partial
    const int pid = ((b * 64 + qt) * 4 + ch);
    unsigned short* pO = Opart + (size_t)pid * 4096 + row * 128 + c0;
    ushort8v p0, p1;
#pragma unroll
    for (int c = 0; c < 8; ++c) { p0[c] = f2bf(o[c]); p1[c] = f2bf(o[8 + c]); }
    *(ushort8v*)(pO) = p0;
    *(ushort8v*)(pO + 8) = p1;
    if ((tid & 7) == 0) {
      mpart[pid * 32 + row] = m_fin;
      lpart[pid * 32 + row] = l_fin;
    }
  }
}

// ---------------------------------------------------------------------------
// Kernel 4: stage-2 combine for qt >= 16. Grid = 4 b x 48 qt = 192 blocks.
// ---------------------------------------------------------------------------
__global__ __launch_bounds__(256) void attn2(const unsigned short* __restrict__ Opart,
                                             const float* __restrict__ mpart,
                                             const float* __restrict__ lpart,
                                             float* __restrict__ out) {
  const int idx = blockIdx.x;
  const int b = idx & 3;
  const int qt = 16 + (idx >> 2);
  const int nch = (qt >> 4) + 1;          // 2..4
  const int tid = threadIdx.x;
  const int row = tid >> 3;
  const int c0  = (tid & 7) * 16;
  const int pbase = (b * 64 + qt) * 4;

  float m_fin = NEG_BIG;
  for (int ch = 0; ch < nch; ++ch)
    m_fin = fmaxf(m_fin, mpart[(pbase + ch) * 32 + row]);
  float l_fin = 0.f;
  float o[16];
#pragma unroll
  for (int c = 0; c < 16; ++c) o[c] = 0.f;
  for (int ch = 0; ch < nch; ++ch) {
    const int pid = pbase + ch;
    const float sc = __builtin_amdgcn_exp2f(mpart[pid * 32 + row] - m_fin);
    l_fin += sc * lpart[pid * 32 + row];
    const unsigned short* pO = Opart + (size_t)pid * 4096 + row * 128 + c0;
    ushort8v p0 = *(const ushort8v*)(pO);
    ushort8v p1 = *(const ushort8v*)(pO + 8);
#pragma unroll
    for (int c = 0; c < 8; ++c) {
      o[c]     += sc * bf2f(p0[c]);
      o[8 + c] += sc * bf2f(p1[c]);
    }
  }
  const float inv = 1.0f / l_fin;
  float* op = out + (size_t)(b * T_ + qt * 32 + row) * H_ + c0;
#pragma unroll
  for (int c = 0; c < 16; c += 4) {
    f32x4 v = {o[c] * inv, o[c + 1] * inv, o[c + 2] * inv, o[c + 3] * inv};
    *(f32x4*)(op + c) = v;
  }
}

// ---------------------------------------------------------------------------
extern "C" void kernel_launch(void* const* d_in, const int* in_sizes, int n_in,
                              void* d_out, int out_size, void* d_ws, size_t ws_size,
                              hipStream_t stream) {
  const float* x  = (const float*)d_in[0];
  const float* Wq = (const float*)d_in[1];
  const float* Wk = (const float*)d_in[2];
  const float* Wv = (const float*)d_in[3];
  float* out = (float*)d_out;

  char* ws = (char*)d_ws;
  unsigned short* xb  = (unsigned short*)(ws);              // [0, 16 MB)
  unsigned short* WbT = (unsigned short*)(ws + 16777216);   // 768 KB
  unsigned short* Qb  = (unsigned short*)(ws + 17563648);   // 2 MB
  unsigned short* Kb  = (unsigned short*)(ws + 19660800);   // 2 MB
  unsigned short* VT  = (unsigned short*)(ws + 21757952);   // 2 MB -> end 23855104
  // attn partials OVERLAY xb (xb dead after qkv_proj; stream-ordered)
  unsigned short* Opart = (unsigned short*)(ws);            // 1024*4096*2 = 8 MB
  float* mpart = (float*)(ws + 8388608);                    // 128 KB
  float* lpart = (float*)(ws + 8519680);                    // 128 KB

  prep<<<dim3(8576), dim3(256), 0, stream>>>(x, Wq, Wk, Wv, xb, WbT);
  qkv_proj<<<dim3(512), dim3(256), 0, stream>>>(xb, WbT, Qb, Kb, VT);
  attn1<<<dim3(1024), dim3(256), 0, stream>>>(Qb, Kb, VT, Opart, mpart, lpart, out);
  attn2<<<dim3(192), dim3(256), 0, stream>>>(Opart, mpart, lpart, out);
}